// Round 2
// baseline (1916.947 us; speedup 1.0000x reference)
//
#include <hip/hip_runtime.h>

#define BATCH 2
#define SEQ   2048
#define DIM   1024
#define NHEAD 16
#define HDIM  64
#define BS_TOT (BATCH * SEQ)  // 4096

// ---------------------------------------------------------------------------
// fp32 SGEMM: C[M,N] = A[M,K] @ B[K,N], 128x128 tile, BK=8, 256 thr, 8x8/thr
// ---------------------------------------------------------------------------
__device__ __forceinline__ void sgemm_body(const float* __restrict__ A,
                                           const float* __restrict__ Bm,
                                           float* __restrict__ C,
                                           int M, int N, int K)
{
    __shared__ float As[8][132];   // [k][m], padded
    __shared__ float Bs[8][132];   // [k][n], padded
    const int tid = threadIdx.x;
    const int tx = tid & 15, ty = tid >> 4;
    const int bn = blockIdx.x * 128, bm = blockIdx.y * 128;
    const int arow = tid >> 1, acol = (tid & 1) * 4;   // A: 128 rows x 8 k
    const int brow = tid >> 5, bcol = (tid & 31) * 4;  // B: 8 k x 128 n

    float acc[8][8] = {};
    const float* Ap = A + (size_t)(bm + arow) * K + acol;
    const float* Bp = Bm + (size_t)brow * N + bn + bcol;

    for (int k0 = 0; k0 < K; k0 += 8) {
        const float4 av = *(const float4*)(Ap + k0);
        const float4 bv = *(const float4*)(Bp + (size_t)k0 * N);
        __syncthreads();  // previous iter's LDS reads done
        As[acol + 0][arow] = av.x;
        As[acol + 1][arow] = av.y;
        As[acol + 2][arow] = av.z;
        As[acol + 3][arow] = av.w;
        *(float4*)&Bs[brow][bcol] = bv;
        __syncthreads();
        #pragma unroll
        for (int kk = 0; kk < 8; ++kk) {
            float a[8], b[8];
            *(float4*)&a[0] = *(const float4*)&As[kk][ty * 8];
            *(float4*)&a[4] = *(const float4*)&As[kk][ty * 8 + 4];
            *(float4*)&b[0] = *(const float4*)&Bs[kk][tx * 8];
            *(float4*)&b[4] = *(const float4*)&Bs[kk][tx * 8 + 4];
            #pragma unroll
            for (int i = 0; i < 8; ++i)
                #pragma unroll
                for (int j = 0; j < 8; ++j)
                    acc[i][j] = fmaf(a[i], b[j], acc[i][j]);
        }
    }
    #pragma unroll
    for (int i = 0; i < 8; ++i) {
        float* cp = C + (size_t)(bm + ty * 8 + i) * N + bn + tx * 8;
        float4 v0 = make_float4(acc[i][0], acc[i][1], acc[i][2], acc[i][3]);
        float4 v1 = make_float4(acc[i][4], acc[i][5], acc[i][6], acc[i][7]);
        *(float4*)cp = v0;
        *(float4*)(cp + 4) = v1;
    }
}

__global__ __launch_bounds__(256) void sgemm_k(const float* __restrict__ A,
                                               const float* __restrict__ Bm,
                                               float* __restrict__ C,
                                               int M, int N, int K)
{
    sgemm_body(A, Bm, C, M, N, K);
}

// Fused Q/K/V projection: blockIdx.z selects which of the three GEMMs.
__global__ __launch_bounds__(256) void qkv_k(const float* __restrict__ qin,
                                             const float* __restrict__ kin,
                                             const float* __restrict__ vin,
                                             const float* __restrict__ wq,
                                             const float* __restrict__ wk,
                                             const float* __restrict__ wv,
                                             float* __restrict__ Qp,
                                             float* __restrict__ Kp,
                                             float* __restrict__ Vp)
{
    const float* A;
    const float* W;
    float* C;
    if (blockIdx.z == 0)      { A = qin; W = wq; C = Qp; }
    else if (blockIdx.z == 1) { A = kin; W = wk; C = Kp; }
    else                      { A = vin; W = wv; C = Vp; }
    sgemm_body(A, W, C, BS_TOT, DIM, DIM);
}

// ---------------------------------------------------------------------------
// Scores kernel: block = (32 q-rows, one (b,h)); loops all k in tiles of 64.
// Writes RAW energies (already * inv_scale) to att, online (m, l) to stats.
// ---------------------------------------------------------------------------
__global__ __launch_bounds__(256) void scores_k(const float* __restrict__ Qp,
                                                const float* __restrict__ Kp,
                                                float* __restrict__ att,
                                                float2* __restrict__ stats)
{
    const int tid = threadIdx.x;
    const int q0 = blockIdx.x * 32;
    const int bh = blockIdx.y;
    const int b = bh >> 4, h = bh & 15;

    __shared__ float Qs[32][68];   // [q][d]
    __shared__ float Kt[64][68];   // [d][k]  (transposed for broadcast reads)
    __shared__ float Ss[32][72];   // score tile staging

    // load Q tile (32x64)
    {
        const int qi = tid >> 3, dq = (tid & 7) * 8;
        const float* src = Qp + ((size_t)b * SEQ + q0 + qi) * DIM + h * HDIM + dq;
        *(float4*)&Qs[qi][dq]     = *(const float4*)src;
        *(float4*)&Qs[qi][dq + 4] = *(const float4*)(src + 4);
    }

    const int tx = tid & 15, ty = tid >> 4;      // compute microtile: 2q x 4k
    const int qi_s = tid >> 3, g = tid & 7;      // stats/write mapping
    const int kjL = tid & 63, dgL = (tid >> 6) * 16;  // K tile load mapping

    float m = -INFINITY, l = 0.f;
    float* attrow = att + ((size_t)bh * SEQ + q0 + qi_s) * SEQ;

    for (int kt = 0; kt < SEQ; kt += 64) {
        // global load K tile (issue early)
        float4 kr[4];
        const float* ksrc = Kp + ((size_t)b * SEQ + kt + kjL) * DIM + h * HDIM + dgL;
        #pragma unroll
        for (int c = 0; c < 4; ++c) kr[c] = *(const float4*)(ksrc + 4 * c);

        __syncthreads();  // prev iter's Kt/Ss consumers done (also covers Qs 1st iter)
        #pragma unroll
        for (int c = 0; c < 4; ++c) {
            const float* kf = (const float*)&kr[c];
            #pragma unroll
            for (int cc = 0; cc < 4; ++cc)
                Kt[dgL + 4 * c + cc][kjL] = kf[cc];
        }
        __syncthreads();

        // 32x64 score tile, 2x4 per thread
        float acc[2][4] = {};
        #pragma unroll
        for (int d = 0; d < HDIM; d += 4) {
            float4 qv0 = *(const float4*)&Qs[2 * ty][d];
            float4 qv1 = *(const float4*)&Qs[2 * ty + 1][d];
            float4 kv[4];
            #pragma unroll
            for (int dd = 0; dd < 4; ++dd) kv[dd] = *(const float4*)&Kt[d + dd][4 * tx];
            const float* q0f = (const float*)&qv0;
            const float* q1f = (const float*)&qv1;
            #pragma unroll
            for (int dd = 0; dd < 4; ++dd) {
                const float* kf = (const float*)&kv[dd];
                #pragma unroll
                for (int j = 0; j < 4; ++j) {
                    acc[0][j] = fmaf(q0f[dd], kf[j], acc[0][j]);
                    acc[1][j] = fmaf(q1f[dd], kf[j], acc[1][j]);
                }
            }
        }
        #pragma unroll
        for (int i = 0; i < 2; ++i)
            #pragma unroll
            for (int j = 0; j < 4; ++j)
                Ss[2 * ty + i][4 * tx + j] = acc[i][j] * 0.125f;  // 1/sqrt(64)
        __syncthreads();

        // online stats + raw score write (8 threads per row, 8 cols each)
        float s8[8];
        *(float4*)&s8[0] = *(const float4*)&Ss[qi_s][g * 8];
        *(float4*)&s8[4] = *(const float4*)&Ss[qi_s][g * 8 + 4];
        float tm = s8[0];
        #pragma unroll
        for (int j = 1; j < 8; ++j) tm = fmaxf(tm, s8[j]);
        #pragma unroll
        for (int o = 1; o < 8; o <<= 1) tm = fmaxf(tm, __shfl_xor(tm, o, 8));
        const float nm = fmaxf(m, tm);
        float ps = 0.f;
        #pragma unroll
        for (int j = 0; j < 8; ++j) ps += __expf(s8[j] - nm);
        #pragma unroll
        for (int o = 1; o < 8; o <<= 1) ps += __shfl_xor(ps, o, 8);
        l = l * __expf(m - nm) + ps;
        m = nm;
        *(float4*)(attrow + kt + g * 8)     = *(const float4*)&s8[0];
        *(float4*)(attrow + kt + g * 8 + 4) = *(const float4*)&s8[4];
    }
    if (g == 0) stats[(size_t)bh * SEQ + q0 + qi_s] = make_float2(m, l);
}

// ---------------------------------------------------------------------------
// Normalize + PV kernel: reads raw scores, writes softmax back to att,
// accumulates attn @ V into OH (merged-head layout [B,S,D]).
// ---------------------------------------------------------------------------
__global__ __launch_bounds__(256) void smpv_k(const float* __restrict__ Vp,
                                              float* __restrict__ att,
                                              const float2* __restrict__ stats,
                                              float* __restrict__ OH)
{
    const int tid = threadIdx.x;
    const int q0 = blockIdx.x * 32;
    const int bh = blockIdx.y;
    const int b = bh >> 4, h = bh & 15;

    __shared__ float Vs[64][68];   // [k][d]
    __shared__ float Ps[32][72];   // softmax'd tile

    const int qi = tid >> 3, g = tid & 7;
    const float2 ml = stats[(size_t)bh * SEQ + q0 + qi];
    const float rl = 1.f / ml.y;
    float* attrow = att + ((size_t)bh * SEQ + q0 + qi) * SEQ;
    const int vkj = tid >> 2, vd = (tid & 3) * 16;

    float oacc[8] = {};
    for (int kt = 0; kt < SEQ; kt += 64) {
        // issue global loads early
        float4 vr[4];
        const float* vsrc = Vp + ((size_t)b * SEQ + kt + vkj) * DIM + h * HDIM + vd;
        #pragma unroll
        for (int c = 0; c < 4; ++c) vr[c] = *(const float4*)(vsrc + 4 * c);
        float p8[8];
        *(float4*)&p8[0] = *(const float4*)(attrow + kt + g * 8);
        *(float4*)&p8[4] = *(const float4*)(attrow + kt + g * 8 + 4);
        #pragma unroll
        for (int j = 0; j < 8; ++j) p8[j] = __expf(p8[j] - ml.x) * rl;

        __syncthreads();  // prev iter's PV reads of Vs/Ps done
        #pragma unroll
        for (int c = 0; c < 4; ++c)
            *(float4*)&Vs[vkj][vd + 4 * c] = vr[c];
        *(float4*)&Ps[qi][g * 8]     = *(const float4*)&p8[0];
        *(float4*)&Ps[qi][g * 8 + 4] = *(const float4*)&p8[4];
        *(float4*)(attrow + kt + g * 8)     = *(const float4*)&p8[0];
        *(float4*)(attrow + kt + g * 8 + 4) = *(const float4*)&p8[4];
        __syncthreads();

        // PV: out[qi][g*8 .. +7] += sum_kj P[qi][kj] * V[kj][...]
        #pragma unroll 8
        for (int kj = 0; kj < 64; ++kj) {
            const float p = Ps[qi][kj];
            const float4 v0 = *(const float4*)&Vs[kj][g * 8];
            const float4 v1 = *(const float4*)&Vs[kj][g * 8 + 4];
            oacc[0] = fmaf(p, v0.x, oacc[0]);
            oacc[1] = fmaf(p, v0.y, oacc[1]);
            oacc[2] = fmaf(p, v0.z, oacc[2]);
            oacc[3] = fmaf(p, v0.w, oacc[3]);
            oacc[4] = fmaf(p, v1.x, oacc[4]);
            oacc[5] = fmaf(p, v1.y, oacc[5]);
            oacc[6] = fmaf(p, v1.z, oacc[6]);
            oacc[7] = fmaf(p, v1.w, oacc[7]);
        }
    }
    float* op = OH + ((size_t)b * SEQ + q0 + qi) * DIM + h * HDIM + g * 8;
    *(float4*)op       = *(const float4*)&oacc[0];
    *(float4*)(op + 4) = *(const float4*)&oacc[4];
}

// ---------------------------------------------------------------------------
extern "C" void kernel_launch(void* const* d_in, const int* in_sizes, int n_in,
                              void* d_out, int out_size, void* d_ws, size_t ws_size,
                              hipStream_t stream)
{
    const float* qin = (const float*)d_in[0];
    const float* kin = (const float*)d_in[1];
    const float* vin = (const float*)d_in[2];
    const float* wq  = (const float*)d_in[3];
    const float* wk  = (const float*)d_in[4];
    const float* wv  = (const float*)d_in[5];
    const float* wo  = (const float*)d_in[6];

    float* x_out = (float*)d_out;                                  // [B,S,D]
    float* att   = x_out + (size_t)BATCH * SEQ * DIM;              // [B,H,S,S]

    const size_t NTOK = (size_t)BS_TOT * DIM;  // 4M floats
    float* Qp = (float*)d_ws;
    float* Kp = Qp + NTOK;
    float* Vp = Kp + NTOK;
    float* OH = Vp + NTOK;
    float2* stats = (float2*)(OH + NTOK);      // [B*H*S] (m, l)

    dim3 blk(256);
    // 1. QKV projections (fused via grid.z)
    qkv_k<<<dim3(DIM / 128, BS_TOT / 128, 3), blk, 0, stream>>>(
        qin, kin, vin, wq, wk, wv, Qp, Kp, Vp);
    // 2. raw scores + softmax stats
    scores_k<<<dim3(SEQ / 32, BATCH * NHEAD), blk, 0, stream>>>(Qp, Kp, att, stats);
    // 3. normalize + PV
    smpv_k<<<dim3(SEQ / 32, BATCH * NHEAD), blk, 0, stream>>>(Vp, att, stats, OH);
    // 4. output projection
    sgemm_k<<<dim3(DIM / 128, BS_TOT / 128), blk, 0, stream>>>(
        OH, wo, x_out, BS_TOT, DIM, DIM);
}

// Round 4
// 968.489 us; speedup vs baseline: 1.9793x; 1.9793x over previous
//
#include <hip/hip_runtime.h>

#define BATCH 2
#define SEQ   2048
#define DIM   1024
#define NHEAD 16
#define HDIM  64
#define BS_TOT (BATCH * SEQ)  // 4096

typedef short bf16x8 __attribute__((ext_vector_type(8)));
typedef float f32x4  __attribute__((ext_vector_type(4)));

// ---------------------------------------------------------------------------
// bf16 helpers
// ---------------------------------------------------------------------------
__device__ __forceinline__ ushort rne_bf16(float v) {
    uint u = __float_as_uint(v);
    return (ushort)((u + 0x7fffu + ((u >> 16) & 1u)) >> 16);
}
__device__ __forceinline__ ushort hi_bf16(float v) {
    return (ushort)(__float_as_uint(v) >> 16);
}
__device__ __forceinline__ ushort lo_bf16(float v) {
    float h = __uint_as_float(__float_as_uint(v) & 0xffff0000u);
    return (ushort)(__float_as_uint(v - h) >> 16);
}
__device__ __forceinline__ uint2 pack_hi4(float4 v) {
    uint x0 = __float_as_uint(v.x), x1 = __float_as_uint(v.y);
    uint x2 = __float_as_uint(v.z), x3 = __float_as_uint(v.w);
    return make_uint2((x0 >> 16) | (x1 & 0xffff0000u),
                      (x2 >> 16) | (x3 & 0xffff0000u));
}
__device__ __forceinline__ float4 rez4(float4 v) {
    float4 r;
    r.x = v.x - __uint_as_float(__float_as_uint(v.x) & 0xffff0000u);
    r.y = v.y - __uint_as_float(__float_as_uint(v.y) & 0xffff0000u);
    r.z = v.z - __uint_as_float(__float_as_uint(v.z) & 0xffff0000u);
    r.w = v.w - __uint_as_float(__float_as_uint(v.w) & 0xffff0000u);
    return r;
}
__device__ __forceinline__ bf16x8 ld_frag(const ushort* p) {
    int4 v = *(const int4*)p;
    return __builtin_bit_cast(bf16x8, v);
}
// Swizzled u16 index into a [64][64] bf16 LDS tile (stride 128B, 16B blocks
// XORed with row&7 -> frag ds_read_b128 at the b128 bank floor).
__device__ __forceinline__ int swz(int row, int col) {
    return row * 64 + ((((col >> 3) ^ row) & 7) << 3) + (col & 7);
}
// Stage a 64x64 u16 tile global->LDS with swizzle. 256 threads.
__device__ __forceinline__ void stage64(ushort* dst, const ushort* src,
                                        int ld, int tid) {
    const int row = tid >> 2, c16 = (tid & 3) * 16;
    const ushort* s = src + (size_t)row * ld + c16;
    uint4 a = *(const uint4*)s;
    uint4 b = *(const uint4*)(s + 8);
    *(uint4*)&dst[swz(row, c16)]     = a;
    *(uint4*)&dst[swz(row, c16 + 8)] = b;
}

// ---------------------------------------------------------------------------
// Weight transpose + hi/lo split: W[K][N] f32 -> WT hi/lo [N][K] bf16 bits.
// wt holds [4][2][DIM*DIM] ushort (wq, wk, wv, wo).
// ---------------------------------------------------------------------------
__global__ __launch_bounds__(256) void wsplit_k(const float* __restrict__ wq,
                                                const float* __restrict__ wk,
                                                const float* __restrict__ wv,
                                                const float* __restrict__ wo,
                                                ushort* __restrict__ wt)
{
    const float* W = (blockIdx.z == 0) ? wq : (blockIdx.z == 1) ? wk
                   : (blockIdx.z == 2) ? wv : wo;
    ushort* hi = wt + (size_t)blockIdx.z * 2 * DIM * DIM;
    ushort* lo = hi + (size_t)DIM * DIM;
    __shared__ float t[32][33];
    const int x = threadIdx.x & 31, y = threadIdx.x >> 5;  // 32 x 8
    const int bx = blockIdx.x * 32, by = blockIdx.y * 32;
    #pragma unroll
    for (int j = 0; j < 32; j += 8)
        t[y + j][x] = W[(size_t)(by + y + j) * DIM + bx + x];
    __syncthreads();
    #pragma unroll
    for (int j = 0; j < 32; j += 8) {
        float v = t[x][y + j];  // W[by+x][bx+y+j] -> WT[bx+y+j][by+x]
        size_t o = (size_t)(bx + y + j) * DIM + by + x;
        hi[o] = hi_bf16(v);
        lo[o] = lo_bf16(v);
    }
}

// ---------------------------------------------------------------------------
// bf16x3 split-MFMA GEMM core: acc = A[M][K]f32 x BT[N][K](pre-split bf16).
// 128x128 tile, BK=32, 256 thr = 4 waves (2x2), per-wave 64x64 = 4x4 frags.
// ---------------------------------------------------------------------------
__device__ __forceinline__ void mfma3_core(const float* __restrict__ A,
                                           const ushort* __restrict__ BThi,
                                           const ushort* __restrict__ BTlo,
                                           int K, int bm, int bn,
                                           f32x4 acc[4][4])
{
    __shared__ __align__(16) ushort Ah[128 * 32], Al[128 * 32];
    __shared__ __align__(16) ushort Bh[128 * 32], Bl[128 * 32];
    const int tid = threadIdx.x;
    const int w = tid >> 6, lane = tid & 63;
    const int m_off = (w >> 1) * 64, n_off = (w & 1) * 64;
    const int r = lane & 15, kg = lane >> 4;

    const int sr = tid >> 1, sk = (tid & 1) * 16;
    const float*  Ap  = A    + (size_t)(bm + sr) * K + sk;
    const ushort* Bhp = BThi + (size_t)(bn + sr) * K + sk;
    const ushort* Blp = BTlo + (size_t)(bn + sr) * K + sk;

    for (int k0 = 0; k0 < K; k0 += 32) {
        float4 a0 = *(const float4*)(Ap + k0);
        float4 a1 = *(const float4*)(Ap + k0 + 4);
        float4 a2 = *(const float4*)(Ap + k0 + 8);
        float4 a3 = *(const float4*)(Ap + k0 + 12);
        int4 bh0 = *(const int4*)(Bhp + k0);
        int4 bh1 = *(const int4*)(Bhp + k0 + 8);
        int4 bl0 = *(const int4*)(Blp + k0);
        int4 bl1 = *(const int4*)(Blp + k0 + 8);

        __syncthreads();
        {
            uint2 h0 = pack_hi4(a0), h1 = pack_hi4(a1);
            uint2 h2 = pack_hi4(a2), h3 = pack_hi4(a3);
            *(uint4*)&Ah[sr * 32 + sk]     = make_uint4(h0.x, h0.y, h1.x, h1.y);
            *(uint4*)&Ah[sr * 32 + sk + 8] = make_uint4(h2.x, h2.y, h3.x, h3.y);
            uint2 l0 = pack_hi4(rez4(a0)), l1 = pack_hi4(rez4(a1));
            uint2 l2 = pack_hi4(rez4(a2)), l3 = pack_hi4(rez4(a3));
            *(uint4*)&Al[sr * 32 + sk]     = make_uint4(l0.x, l0.y, l1.x, l1.y);
            *(uint4*)&Al[sr * 32 + sk + 8] = make_uint4(l2.x, l2.y, l3.x, l3.y);
            *(int4*)&Bh[sr * 32 + sk]     = bh0;
            *(int4*)&Bh[sr * 32 + sk + 8] = bh1;
            *(int4*)&Bl[sr * 32 + sk]     = bl0;
            *(int4*)&Bl[sr * 32 + sk + 8] = bl1;
        }
        __syncthreads();

        bf16x8 ah[4], al[4], bh[4], bl[4];
        #pragma unroll
        for (int mi = 0; mi < 4; ++mi) {
            const int row = (m_off + mi * 16 + r) * 32 + kg * 8;
            ah[mi] = ld_frag(&Ah[row]);
            al[mi] = ld_frag(&Al[row]);
        }
        #pragma unroll
        for (int nj = 0; nj < 4; ++nj) {
            const int row = (n_off + nj * 16 + r) * 32 + kg * 8;
            bh[nj] = ld_frag(&Bh[row]);
            bl[nj] = ld_frag(&Bl[row]);
        }
        #pragma unroll
        for (int mi = 0; mi < 4; ++mi)
            #pragma unroll
            for (int nj = 0; nj < 4; ++nj) {
                acc[mi][nj] = __builtin_amdgcn_mfma_f32_16x16x32_bf16(ah[mi], bh[nj], acc[mi][nj], 0, 0, 0);
                acc[mi][nj] = __builtin_amdgcn_mfma_f32_16x16x32_bf16(ah[mi], bl[nj], acc[mi][nj], 0, 0, 0);
                acc[mi][nj] = __builtin_amdgcn_mfma_f32_16x16x32_bf16(al[mi], bh[nj], acc[mi][nj], 0, 0, 0);
            }
    }
}

// QKV projections: epilogue writes split (hi/lo) or RNE bf16 planes.
__global__ __launch_bounds__(256) void qkvsplit_k(const float* __restrict__ qin,
                                                  const float* __restrict__ kin,
                                                  const float* __restrict__ vin,
                                                  const ushort* __restrict__ wt,
                                                  ushort* __restrict__ Qh, ushort* __restrict__ Ql,
                                                  ushort* __restrict__ Kh, ushort* __restrict__ Kl,
                                                  ushort* __restrict__ Vh)
{
    const float* A;
    ushort *hi, *lo;
    if (blockIdx.z == 0)      { A = qin; hi = Qh; lo = Ql; }
    else if (blockIdx.z == 1) { A = kin; hi = Kh; lo = Kl; }
    else                      { A = vin; hi = Vh; lo = nullptr; }
    const ushort* bt = wt + (size_t)blockIdx.z * 2 * DIM * DIM;
    const int bm = blockIdx.y * 128, bn = blockIdx.x * 128;
    f32x4 acc[4][4] = {};
    mfma3_core(A, bt, bt + (size_t)DIM * DIM, DIM, bm, bn, acc);

    const int lane = threadIdx.x & 63, w = threadIdx.x >> 6;
    const int m_off = (w >> 1) * 64, n_off = (w & 1) * 64;
    const int r = lane & 15, kg = lane >> 4;
    #pragma unroll
    for (int mi = 0; mi < 4; ++mi)
        #pragma unroll
        for (int nj = 0; nj < 4; ++nj) {
            const int row = bm + m_off + mi * 16 + kg * 4;
            const int col = bn + n_off + nj * 16 + r;
            #pragma unroll
            for (int j = 0; j < 4; ++j) {
                float v = acc[mi][nj][j];
                size_t o = (size_t)(row + j) * DIM + col;
                if (lo) { hi[o] = hi_bf16(v); lo[o] = lo_bf16(v); }
                else    { hi[o] = rne_bf16(v); }
            }
        }
}

// Output projection: OH f32 x woT(split) -> x_out f32.
__global__ __launch_bounds__(256) void mfma3_out_k(const float* __restrict__ OH,
                                                   const ushort* __restrict__ wt,
                                                   float* __restrict__ xo)
{
    const ushort* bt = wt + (size_t)3 * 2 * DIM * DIM;
    const int bm = blockIdx.y * 128, bn = blockIdx.x * 128;
    f32x4 acc[4][4] = {};
    mfma3_core(OH, bt, bt + (size_t)DIM * DIM, DIM, bm, bn, acc);

    const int lane = threadIdx.x & 63, w = threadIdx.x >> 6;
    const int m_off = (w >> 1) * 64, n_off = (w & 1) * 64;
    const int r = lane & 15, kg = lane >> 4;
    #pragma unroll
    for (int mi = 0; mi < 4; ++mi)
        #pragma unroll
        for (int nj = 0; nj < 4; ++nj) {
            const int row = bm + m_off + mi * 16 + kg * 4;
            const int col = bn + n_off + nj * 16 + r;
            #pragma unroll
            for (int j = 0; j < 4; ++j)
                xo[(size_t)(row + j) * DIM + col] = acc[mi][nj][j];
        }
}

// ---------------------------------------------------------------------------
// Attention pass 1: per-row online (m,l) via plain-bf16 MFMA QK^T.
// Block = 64 q-rows of one (b,h); 4 waves x 16 q-rows.
// ---------------------------------------------------------------------------
__global__ __launch_bounds__(256) void attn_pass1(const ushort* __restrict__ Qh,
                                                  const ushort* __restrict__ Kh,
                                                  float2* __restrict__ stats)
{
    __shared__ __align__(16) ushort sQ[64 * 64], sK[64 * 64];
    const int tid = threadIdx.x, w = tid >> 6, lane = tid & 63;
    const int r = lane & 15, kg = lane >> 4;
    const int q0 = blockIdx.x * 64, bh = blockIdx.y, b = bh >> 4, h = bh & 15;

    stage64(sQ, Qh + ((size_t)b * SEQ + q0) * DIM + h * HDIM, DIM, tid);
    __syncthreads();
    bf16x8 qf[2];
    #pragma unroll
    for (int ks = 0; ks < 2; ++ks)
        qf[ks] = ld_frag(&sQ[swz(w * 16 + r, ks * 32 + kg * 8)]);

    float m[4], l[4];
    #pragma unroll
    for (int j = 0; j < 4; ++j) { m[j] = -INFINITY; l[j] = 0.f; }

    const int srow = tid >> 2, sc16 = (tid & 3) * 16;
    for (int kt = 0; kt < SEQ; kt += 64) {
        const ushort* ksrc = Kh + ((size_t)b * SEQ + kt + srow) * DIM + h * HDIM + sc16;
        uint4 ka = *(const uint4*)ksrc;
        uint4 kb = *(const uint4*)(ksrc + 8);
        __syncthreads();
        *(uint4*)&sK[swz(srow, sc16)]     = ka;
        *(uint4*)&sK[swz(srow, sc16 + 8)] = kb;
        __syncthreads();

        f32x4 acc[4] = {};
        #pragma unroll
        for (int ks = 0; ks < 2; ++ks)
            #pragma unroll
            for (int nj = 0; nj < 4; ++nj) {
                bf16x8 kf = ld_frag(&sK[swz(nj * 16 + r, ks * 32 + kg * 8)]);
                acc[nj] = __builtin_amdgcn_mfma_f32_16x16x32_bf16(qf[ks], kf, acc[nj], 0, 0, 0);
            }
        #pragma unroll
        for (int j = 0; j < 4; ++j) {
            float s0 = acc[0][j] * 0.125f, s1 = acc[1][j] * 0.125f;
            float s2 = acc[2][j] * 0.125f, s3 = acc[3][j] * 0.125f;
            float tm = fmaxf(fmaxf(s0, s1), fmaxf(s2, s3));
            #pragma unroll
            for (int o = 1; o < 16; o <<= 1) tm = fmaxf(tm, __shfl_xor(tm, o));
            const float nm = fmaxf(m[j], tm);
            float ps = __expf(s0 - nm) + __expf(s1 - nm) + __expf(s2 - nm) + __expf(s3 - nm);
            #pragma unroll
            for (int o = 1; o < 16; o <<= 1) ps += __shfl_xor(ps, o);
            l[j] = l[j] * __expf(m[j] - nm) + ps;
            m[j] = nm;
        }
    }
    if (r == 0) {
        #pragma unroll
        for (int j = 0; j < 4; ++j)
            stats[(size_t)bh * SEQ + q0 + w * 16 + kg * 4 + j] = make_float2(m[j], l[j]);
    }
}

// ---------------------------------------------------------------------------
// Attention pass 2: recompute s (bf16x3), write normalized P to att (f32),
// P->bf16 through LDS, PV via MFMA (V transposed in LDS) -> OH.
// ---------------------------------------------------------------------------
__global__ __launch_bounds__(256) void attn_pass2(const ushort* __restrict__ Qh,
                                                  const ushort* __restrict__ Ql,
                                                  const ushort* __restrict__ Kh,
                                                  const ushort* __restrict__ Kl,
                                                  const ushort* __restrict__ Vh,
                                                  const float2* __restrict__ stats,
                                                  float* __restrict__ att,
                                                  float* __restrict__ OH)
{
    __shared__ __align__(16) ushort sQh[64 * 64], sQl[64 * 64];
    __shared__ __align__(16) ushort sKh[64 * 64], sKl[64 * 64];
    __shared__ __align__(16) ushort sVt[64 * 64], sPs[64 * 64];
    const int tid = threadIdx.x, w = tid >> 6, lane = tid & 63;
    const int r = lane & 15, kg = lane >> 4;
    const int q0 = blockIdx.x * 64, bh = blockIdx.y, b = bh >> 4, h = bh & 15;

    stage64(sQh, Qh + ((size_t)b * SEQ + q0) * DIM + h * HDIM, DIM, tid);
    stage64(sQl, Ql + ((size_t)b * SEQ + q0) * DIM + h * HDIM, DIM, tid);
    __syncthreads();
    bf16x8 qh[2], ql[2];
    #pragma unroll
    for (int ks = 0; ks < 2; ++ks) {
        qh[ks] = ld_frag(&sQh[swz(w * 16 + r, ks * 32 + kg * 8)]);
        ql[ks] = ld_frag(&sQl[swz(w * 16 + r, ks * 32 + kg * 8)]);
    }
    float mr[4], rl[4];
    #pragma unroll
    for (int j = 0; j < 4; ++j) {
        float2 ml = stats[(size_t)bh * SEQ + q0 + w * 16 + kg * 4 + j];
        mr[j] = ml.x; rl[j] = 1.f / ml.y;
    }
    f32x4 accO[4] = {};

    const int srow = tid >> 2, sc16 = (tid & 3) * 16;      // K staging map
    const int vk = tid & 63, vd0 = (tid >> 6) * 16;        // V staging map

    for (int kt = 0; kt < SEQ; kt += 64) {
        const size_t krow = ((size_t)b * SEQ + kt + srow) * DIM + h * HDIM + sc16;
        uint4 kh0 = *(const uint4*)(Kh + krow);
        uint4 kh1 = *(const uint4*)(Kh + krow + 8);
        uint4 kl0 = *(const uint4*)(Kl + krow);
        uint4 kl1 = *(const uint4*)(Kl + krow + 8);
        const size_t vrow = ((size_t)b * SEQ + kt + vk) * DIM + h * HDIM + vd0;
        uint4 v0 = *(const uint4*)(Vh + vrow);
        uint4 v1 = *(const uint4*)(Vh + vrow + 8);

        __syncthreads();   // prev iter's sK/sVt/sPs consumers done
        *(uint4*)&sKh[swz(srow, sc16)]     = kh0;
        *(uint4*)&sKh[swz(srow, sc16 + 8)] = kh1;
        *(uint4*)&sKl[swz(srow, sc16)]     = kl0;
        *(uint4*)&sKl[swz(srow, sc16 + 8)] = kl1;
        {
            ushort e[16];
            *(uint4*)&e[0] = v0;
            *(uint4*)&e[8] = v1;
            #pragma unroll
            for (int i = 0; i < 16; ++i)
                sVt[swz(vd0 + i, vk)] = e[i];   // transpose: row=d, col=k
        }
        __syncthreads();

        // QK^T (bf16x3)
        f32x4 accS[4] = {};
        #pragma unroll
        for (int ks = 0; ks < 2; ++ks)
            #pragma unroll
            for (int nj = 0; nj < 4; ++nj) {
                bf16x8 kh = ld_frag(&sKh[swz(nj * 16 + r, ks * 32 + kg * 8)]);
                bf16x8 kl = ld_frag(&sKl[swz(nj * 16 + r, ks * 32 + kg * 8)]);
                accS[nj] = __builtin_amdgcn_mfma_f32_16x16x32_bf16(qh[ks], kh, accS[nj], 0, 0, 0);
                accS[nj] = __builtin_amdgcn_mfma_f32_16x16x32_bf16(ql[ks], kh, accS[nj], 0, 0, 0);
                accS[nj] = __builtin_amdgcn_mfma_f32_16x16x32_bf16(qh[ks], kl, accS[nj], 0, 0, 0);
            }
        // P = exp(s-m)/l : write att f32 + sPs bf16
        #pragma unroll
        for (int nj = 0; nj < 4; ++nj)
            #pragma unroll
            for (int j = 0; j < 4; ++j) {
                float p = __expf(accS[nj][j] * 0.125f - mr[j]) * rl[j];
                const int qrow = w * 16 + kg * 4 + j;
                att[((size_t)bh * SEQ + q0 + qrow) * SEQ + kt + nj * 16 + r] = p;
                sPs[swz(qrow, nj * 16 + r)] = rne_bf16(p);
            }
        __syncthreads();   // sPs visible

        // PV
        bf16x8 pa0 = ld_frag(&sPs[swz(w * 16 + r, kg * 8)]);
        bf16x8 pa1 = ld_frag(&sPs[swz(w * 16 + r, 32 + kg * 8)]);
        #pragma unroll
        for (int nj = 0; nj < 4; ++nj) {
            bf16x8 vb0 = ld_frag(&sVt[swz(nj * 16 + r, kg * 8)]);
            bf16x8 vb1 = ld_frag(&sVt[swz(nj * 16 + r, 32 + kg * 8)]);
            accO[nj] = __builtin_amdgcn_mfma_f32_16x16x32_bf16(pa0, vb0, accO[nj], 0, 0, 0);
            accO[nj] = __builtin_amdgcn_mfma_f32_16x16x32_bf16(pa1, vb1, accO[nj], 0, 0, 0);
        }
    }
    #pragma unroll
    for (int nj = 0; nj < 4; ++nj)
        #pragma unroll
        for (int j = 0; j < 4; ++j)
            OH[((size_t)b * SEQ + q0 + w * 16 + kg * 4 + j) * DIM + h * HDIM + nj * 16 + r] = accO[nj][j];
}

// ===========================================================================
// fp32 fallback path (benched R2: passed, 1917 us) — used if ws too small.
// ===========================================================================
__device__ __forceinline__ void sgemm_body(const float* __restrict__ A,
                                           const float* __restrict__ Bm,
                                           float* __restrict__ C,
                                           int M, int N, int K)
{
    __shared__ float As[8][132];
    __shared__ float Bs[8][132];
    const int tid = threadIdx.x;
    const int tx = tid & 15, ty = tid >> 4;
    const int bn = blockIdx.x * 128, bm = blockIdx.y * 128;
    const int arow = tid >> 1, acol = (tid & 1) * 4;
    const int brow = tid >> 5, bcol = (tid & 31) * 4;
    float acc[8][8] = {};
    const float* Ap = A + (size_t)(bm + arow) * K + acol;
    const float* Bp = Bm + (size_t)brow * N + bn + bcol;
    for (int k0 = 0; k0 < K; k0 += 8) {
        const float4 av = *(const float4*)(Ap + k0);
        const float4 bv = *(const float4*)(Bp + (size_t)k0 * N);
        __syncthreads();
        As[acol + 0][arow] = av.x;
        As[acol + 1][arow] = av.y;
        As[acol + 2][arow] = av.z;
        As[acol + 3][arow] = av.w;
        *(float4*)&Bs[brow][bcol] = bv;
        __syncthreads();
        #pragma unroll
        for (int kk = 0; kk < 8; ++kk) {
            float a[8], bb[8];
            *(float4*)&a[0] = *(const float4*)&As[kk][ty * 8];
            *(float4*)&a[4] = *(const float4*)&As[kk][ty * 8 + 4];
            *(float4*)&bb[0] = *(const float4*)&Bs[kk][tx * 8];
            *(float4*)&bb[4] = *(const float4*)&Bs[kk][tx * 8 + 4];
            #pragma unroll
            for (int i = 0; i < 8; ++i)
                #pragma unroll
                for (int j = 0; j < 8; ++j)
                    acc[i][j] = fmaf(a[i], bb[j], acc[i][j]);
        }
    }
    #pragma unroll
    for (int i = 0; i < 8; ++i) {
        float* cp = C + (size_t)(bm + ty * 8 + i) * N + bn + tx * 8;
        *(float4*)cp = make_float4(acc[i][0], acc[i][1], acc[i][2], acc[i][3]);
        *(float4*)(cp + 4) = make_float4(acc[i][4], acc[i][5], acc[i][6], acc[i][7]);
    }
}
__global__ __launch_bounds__(256) void sgemm_k(const float* __restrict__ A,
                                               const float* __restrict__ Bm,
                                               float* __restrict__ C,
                                               int M, int N, int K)
{ sgemm_body(A, Bm, C, M, N, K); }

__global__ __launch_bounds__(256) void qkv_k(const float* __restrict__ qin,
                                             const float* __restrict__ kin,
                                             const float* __restrict__ vin,
                                             const float* __restrict__ wq,
                                             const float* __restrict__ wk,
                                             const float* __restrict__ wv,
                                             float* __restrict__ Qp,
                                             float* __restrict__ Kp,
                                             float* __restrict__ Vp)
{
    const float* A; const float* W; float* C;
    if (blockIdx.z == 0)      { A = qin; W = wq; C = Qp; }
    else if (blockIdx.z == 1) { A = kin; W = wk; C = Kp; }
    else                      { A = vin; W = wv; C = Vp; }
    sgemm_body(A, W, C, BS_TOT, DIM, DIM);
}

__global__ __launch_bounds__(256) void scores_k(const float* __restrict__ Qp,
                                                const float* __restrict__ Kp,
                                                float* __restrict__ att,
                                                float2* __restrict__ stats)
{
    const int tid = threadIdx.x;
    const int q0 = blockIdx.x * 32;
    const int bh = blockIdx.y;
    const int b = bh >> 4, h = bh & 15;
    __shared__ float Qs[32][68];
    __shared__ float Kt[64][68];
    __shared__ float Ss[32][72];
    {
        const int qi = tid >> 3, dq = (tid & 7) * 8;
        const float* src = Qp + ((size_t)b * SEQ + q0 + qi) * DIM + h * HDIM + dq;
        *(float4*)&Qs[qi][dq]     = *(const float4*)src;
        *(float4*)&Qs[qi][dq + 4] = *(const float4*)(src + 4);
    }
    const int tx = tid & 15, ty = tid >> 4;
    const int qi_s = tid >> 3, g = tid & 7;
    const int kjL = tid & 63, dgL = (tid >> 6) * 16;
    float m = -INFINITY, l = 0.f;
    float* attrow = att + ((size_t)bh * SEQ + q0 + qi_s) * SEQ;
    for (int kt = 0; kt < SEQ; kt += 64) {
        float4 kr[4];
        const float* ksrc = Kp + ((size_t)b * SEQ + kt + kjL) * DIM + h * HDIM + dgL;
        #pragma unroll
        for (int c = 0; c < 4; ++c) kr[c] = *(const float4*)(ksrc + 4 * c);
        __syncthreads();
        #pragma unroll
        for (int c = 0; c < 4; ++c) {
            const float* kf = (const float*)&kr[c];
            #pragma unroll
            for (int cc = 0; cc < 4; ++cc)
                Kt[dgL + 4 * c + cc][kjL] = kf[cc];
        }
        __syncthreads();
        float acc[2][4] = {};
        #pragma unroll
        for (int d = 0; d < HDIM; d += 4) {
            float4 qv0 = *(const float4*)&Qs[2 * ty][d];
            float4 qv1 = *(const float4*)&Qs[2 * ty + 1][d];
            float4 kv[4];
            #pragma unroll
            for (int dd = 0; dd < 4; ++dd) kv[dd] = *(const float4*)&Kt[d + dd][4 * tx];
            const float* q0f = (const float*)&qv0;
            const float* q1f = (const float*)&qv1;
            #pragma unroll
            for (int dd = 0; dd < 4; ++dd) {
                const float* kf = (const float*)&kv[dd];
                #pragma unroll
                for (int j = 0; j < 4; ++j) {
                    acc[0][j] = fmaf(q0f[dd], kf[j], acc[0][j]);
                    acc[1][j] = fmaf(q1f[dd], kf[j], acc[1][j]);
                }
            }
        }
        #pragma unroll
        for (int i = 0; i < 2; ++i)
            #pragma unroll
            for (int j = 0; j < 4; ++j)
                Ss[2 * ty + i][4 * tx + j] = acc[i][j] * 0.125f;
        __syncthreads();
        float s8[8];
        *(float4*)&s8[0] = *(const float4*)&Ss[qi_s][g * 8];
        *(float4*)&s8[4] = *(const float4*)&Ss[qi_s][g * 8 + 4];
        float tm = s8[0];
        #pragma unroll
        for (int j = 1; j < 8; ++j) tm = fmaxf(tm, s8[j]);
        #pragma unroll
        for (int o = 1; o < 8; o <<= 1) tm = fmaxf(tm, __shfl_xor(tm, o, 8));
        const float nm = fmaxf(m, tm);
        float ps = 0.f;
        #pragma unroll
        for (int j = 0; j < 8; ++j) ps += __expf(s8[j] - nm);
        #pragma unroll
        for (int o = 1; o < 8; o <<= 1) ps += __shfl_xor(ps, o, 8);
        l = l * __expf(m - nm) + ps;
        m = nm;
        *(float4*)(attrow + kt + g * 8)     = *(const float4*)&s8[0];
        *(float4*)(attrow + kt + g * 8 + 4) = *(const float4*)&s8[4];
    }
    if (g == 0) stats[(size_t)bh * SEQ + q0 + qi_s] = make_float2(m, l);
}

__global__ __launch_bounds__(256) void smpv_k(const float* __restrict__ Vp,
                                              float* __restrict__ att,
                                              const float2* __restrict__ stats,
                                              float* __restrict__ OH)
{
    const int tid = threadIdx.x;
    const int q0 = blockIdx.x * 32;
    const int bh = blockIdx.y;
    const int b = bh >> 4, h = bh & 15;
    __shared__ float Vs[64][68];
    __shared__ float Ps[32][72];
    const int qi = tid >> 3, g = tid & 7;
    const float2 ml = stats[(size_t)bh * SEQ + q0 + qi];
    const float rl = 1.f / ml.y;
    float* attrow = att + ((size_t)bh * SEQ + q0 + qi) * SEQ;
    const int vkj = tid >> 2, vd = (tid & 3) * 16;
    float oacc[8] = {};
    for (int kt = 0; kt < SEQ; kt += 64) {
        float4 vr[4];
        const float* vsrc = Vp + ((size_t)b * SEQ + kt + vkj) * DIM + h * HDIM + vd;
        #pragma unroll
        for (int c = 0; c < 4; ++c) vr[c] = *(const float4*)(vsrc + 4 * c);
        float p8[8];
        *(float4*)&p8[0] = *(const float4*)(attrow + kt + g * 8);
        *(float4*)&p8[4] = *(const float4*)(attrow + kt + g * 8 + 4);
        #pragma unroll
        for (int j = 0; j < 8; ++j) p8[j] = __expf(p8[j] - ml.x) * rl;
        __syncthreads();
        #pragma unroll
        for (int c = 0; c < 4; ++c)
            *(float4*)&Vs[vkj][vd + 4 * c] = vr[c];
        *(float4*)&Ps[qi][g * 8]     = *(const float4*)&p8[0];
        *(float4*)&Ps[qi][g * 8 + 4] = *(const float4*)&p8[4];
        *(float4*)(attrow + kt + g * 8)     = *(const float4*)&p8[0];
        *(float4*)(attrow + kt + g * 8 + 4) = *(const float4*)&p8[4];
        __syncthreads();
        #pragma unroll 8
        for (int kj = 0; kj < 64; ++kj) {
            const float p = Ps[qi][kj];
            const float4 v0 = *(const float4*)&Vs[kj][g * 8];
            const float4 v1 = *(const float4*)&Vs[kj][g * 8 + 4];
            oacc[0] = fmaf(p, v0.x, oacc[0]);
            oacc[1] = fmaf(p, v0.y, oacc[1]);
            oacc[2] = fmaf(p, v0.z, oacc[2]);
            oacc[3] = fmaf(p, v0.w, oacc[3]);
            oacc[4] = fmaf(p, v1.x, oacc[4]);
            oacc[5] = fmaf(p, v1.y, oacc[5]);
            oacc[6] = fmaf(p, v1.z, oacc[6]);
            oacc[7] = fmaf(p, v1.w, oacc[7]);
        }
    }
    float* op = OH + ((size_t)b * SEQ + q0 + qi) * DIM + h * HDIM + g * 8;
    *(float4*)op       = *(const float4*)&oacc[0];
    *(float4*)(op + 4) = *(const float4*)&oacc[4];
}

// ---------------------------------------------------------------------------
extern "C" void kernel_launch(void* const* d_in, const int* in_sizes, int n_in,
                              void* d_out, int out_size, void* d_ws, size_t ws_size,
                              hipStream_t stream)
{
    const float* qin = (const float*)d_in[0];
    const float* kin = (const float*)d_in[1];
    const float* vin = (const float*)d_in[2];
    const float* wq  = (const float*)d_in[3];
    const float* wk  = (const float*)d_in[4];
    const float* wv  = (const float*)d_in[5];
    const float* wo  = (const float*)d_in[6];

    float* x_out = (float*)d_out;
    float* att   = x_out + (size_t)BATCH * SEQ * DIM;

    const size_t NTOK = (size_t)BS_TOT * DIM;                      // 4M elems
    const size_t need_fast = 8 * NTOK * 2    /* wt (16MB) */
                           + 5 * NTOK * 2    /* Qh,Ql,Kh,Kl,Vh */
                           + NTOK * 4        /* OH */
                           + (size_t)BATCH * NHEAD * SEQ * 8;      /* stats */
    dim3 blk(256);

    if (ws_size >= need_fast) {
        ushort* wt = (ushort*)d_ws;                                // 8M u16
        ushort* Qh = wt + 8 * NTOK;
        ushort* Ql = Qh + NTOK;
        ushort* Kh = Ql + NTOK;
        ushort* Kl = Kh + NTOK;
        ushort* Vh = Kl + NTOK;
        float*  OH = (float*)(Vh + NTOK);
        float2* stats = (float2*)(OH + NTOK);

        wsplit_k<<<dim3(32, 32, 4), blk, 0, stream>>>(wq, wk, wv, wo, wt);
        qkvsplit_k<<<dim3(DIM / 128, BS_TOT / 128, 3), blk, 0, stream>>>(
            qin, kin, vin, wt, Qh, Ql, Kh, Kl, Vh);
        attn_pass1<<<dim3(SEQ / 64, BATCH * NHEAD), blk, 0, stream>>>(Qh, Kh, stats);
        attn_pass2<<<dim3(SEQ / 64, BATCH * NHEAD), blk, 0, stream>>>(
            Qh, Ql, Kh, Kl, Vh, stats, att, OH);
        mfma3_out_k<<<dim3(DIM / 128, BS_TOT / 128), blk, 0, stream>>>(OH, wt, x_out);
    } else {
        // fp32 fallback (R2-benched path)
        float* Qp = (float*)d_ws;
        float* Kp = Qp + NTOK;
        float* Vp = Kp + NTOK;
        float* OH = Vp + NTOK;
        float2* stats = (float2*)(OH + NTOK);
        qkv_k<<<dim3(DIM / 128, BS_TOT / 128, 3), blk, 0, stream>>>(
            qin, kin, vin, wq, wk, wv, Qp, Kp, Vp);
        scores_k<<<dim3(SEQ / 32, BATCH * NHEAD), blk, 0, stream>>>(Qp, Kp, att, stats);
        smpv_k<<<dim3(SEQ / 32, BATCH * NHEAD), blk, 0, stream>>>(Vp, att, stats, OH);
        sgemm_k<<<dim3(DIM / 128, BS_TOT / 128), blk, 0, stream>>>(
            OH, wo, x_out, BS_TOT, DIM, DIM);
    }
}